// Round 8
// baseline (82.858 us; speedup 1.0000x reference)
//
#include <hip/hip_runtime.h>

// B=64, D=2048, UNITS=1024, NW=64; L = in_sizes[3]/(UNITS*NW) (~56).
//
// out[b,u] = sum_i x[b,i] * W[u,i] + bias[u], W[u,i] = w[k] where bucket k of
// unit u contains position i (indices 1-shifted, 0 = pad). Buckets partition
// positions per unit -> LDS scatter builds W[u,:] race-free.
//
// R8 vs R7 post-mortem: R7 was neutral because 512 blocks x 8 waves at
// 2 blocks/CU = 16 waves/CU — identical occupancy to R4. The only lever that
// has ever moved this kernel is resident-wave count (R3->R4: 8->16 waves/CU
// halved time; all prefetch/dbuf attempts neutral or spilled). R8 doubles
// again to the HW max: U=2, batch-split 2 -> 1024 blocks x 512 thr =
// 4 blocks/CU x 8 waves = 32 waves/CU. LDS 16.6KB x 4 = 66KB OK; live set
// ~35 regs -> ~56 VGPR -> 8 waves/SIMD OK. Costs: indices read 2x (29 MB,
// 2nd copy L3-served), x re-read 268 MB total but L2-resident.

#define B_DIM   64
#define D_DIM   2048
#define D4      (D_DIM / 4)     // 512 float4 per row
#define UNITS_N 1024
#define NW_N    64
#define U_PER_BLOCK 2
#define B_SPLIT 2
#define B_PER_BLOCK (B_DIM / B_SPLIT)               // 32
#define THREADS 512
#define WAVES   (THREADS / 64)                      // 8
#define PAIRS_PER_WAVE (U_PER_BLOCK * NW_N / WAVES) // 16
#define ROWS_PER_WAVE  (B_PER_BLOCK / WAVES)        // 4
#define STEPS   (D4 / 64)                           // 8

__global__ __launch_bounds__(THREADS)   // NO 2nd arg: 64-VGPR cap + spill (R5)
void EfficientHashedLinear_72043781423546_kernel(
    const float* __restrict__ x,        // (64, 2048)
    const float* __restrict__ w,        // (64,)
    const float* __restrict__ bias,     // (1024,)
    const int*   __restrict__ indices,  // (UNITS, NW, L) int32
    float*       __restrict__ out,      // (64, 1024)
    int L)
{
    __shared__ float rows[U_PER_BLOCK][D_DIM];   // 16.4 KB
    __shared__ float w_lds[NW_N];

    const int tid  = threadIdx.x;
    const int wave = tid >> 6;          // 0..7
    const int lane = tid & 63;
    const int u0   = blockIdx.x * U_PER_BLOCK;
    const int bh   = blockIdx.y;        // batch half: 0 or 1

    // Phase 0: zero rows (float4), stage w.
    {
        float4* r4 = (float4*)rows;
        const float4 z = make_float4(0.f, 0.f, 0.f, 0.f);
        #pragma unroll
        for (int i = tid; i < U_PER_BLOCK * D4; i += THREADS)
            r4[i] = z;
        if (tid < NW_N) w_lds[tid] = w[tid];
    }

    // Phase 1a: index load pass — 16 independent lane-predicated loads/wave,
    // all issued before any use.
    int idxv[PAIRS_PER_WAVE];
    #pragma unroll
    for (int p = 0; p < PAIRS_PER_WAVE; ++p) {
        const int pair = wave * PAIRS_PER_WAVE + p;   // 0..127
        const int uu   = pair >> 6;                   // 0..1
        const int k    = pair & 63;                   // 0..63
        const int* bp  = indices + ((size_t)(u0 + uu) * NW_N + k) * L;
        idxv[p] = (lane < L) ? bp[lane] : 0;
    }

    __syncthreads();   // rows[] zeroed before scatter

    // Phase 1b: scatter pass (LDS only).
    #pragma unroll
    for (int p = 0; p < PAIRS_PER_WAVE; ++p) {
        const int pair = wave * PAIRS_PER_WAVE + p;
        const int uu   = pair >> 6;
        const int k    = pair & 63;
        if (idxv[p] > 0) rows[uu][idxv[p] - 1] = w_lds[k];
    }
    // Generic tail for L > 64 (not expected with this data; kept for safety).
    if (L > 64) {
        #pragma unroll 1
        for (int p = 0; p < PAIRS_PER_WAVE; ++p) {
            const int pair = wave * PAIRS_PER_WAVE + p;
            const int uu   = pair >> 6;
            const int k    = pair & 63;
            const int* bp  = indices + ((size_t)(u0 + uu) * NW_N + k) * L;
            const float wk = w_lds[k];
            for (int l = 64 + lane; l < L; l += 64) {
                int idx = bp[l];
                if (idx > 0) rows[uu][idx - 1] = wk;
            }
        }
    }
    __syncthreads();

    // Phase 2: wave owns 4 batch rows (of this half's 32) x 2 units.
    const int b0 = bh * B_PER_BLOCK + wave * ROWS_PER_WAVE;
    const float4* x4 = (const float4*)x;

    float acc[ROWS_PER_WAVE][U_PER_BLOCK];
    #pragma unroll
    for (int bj = 0; bj < ROWS_PER_WAVE; ++bj)
        #pragma unroll
        for (int uu = 0; uu < U_PER_BLOCK; ++uu)
            acc[bj][uu] = 0.0f;

    #pragma unroll 1   // keep live set small; big unrolls hit the 64 cliff
    for (int step = 0; step < STEPS; ++step) {
        const int i4 = step * 64 + lane;          // 0..511
        float4 rv[U_PER_BLOCK];
        #pragma unroll
        for (int uu = 0; uu < U_PER_BLOCK; ++uu)
            rv[uu] = ((const float4*)rows[uu])[i4];   // ds_read_b128
        #pragma unroll
        for (int bj = 0; bj < ROWS_PER_WAVE; ++bj) {
            const float4 xv = x4[(b0 + bj) * D4 + i4];
            #pragma unroll
            for (int uu = 0; uu < U_PER_BLOCK; ++uu) {
                acc[bj][uu] += xv.x * rv[uu].x;
                acc[bj][uu] += xv.y * rv[uu].y;
                acc[bj][uu] += xv.z * rv[uu].z;
                acc[bj][uu] += xv.w * rv[uu].w;
            }
        }
    }

    // Phase 3: butterfly reduce, add bias, store (8 outputs/wave).
    #pragma unroll
    for (int bj = 0; bj < ROWS_PER_WAVE; ++bj) {
        #pragma unroll
        for (int uu = 0; uu < U_PER_BLOCK; ++uu) {
            float v = acc[bj][uu];
            #pragma unroll
            for (int off = 32; off > 0; off >>= 1)
                v += __shfl_down(v, off, 64);
            if (lane == 0)
                out[(b0 + bj) * UNITS_N + (u0 + uu)] = v + bias[u0 + uu];
        }
    }
}

extern "C" void kernel_launch(void* const* d_in, const int* in_sizes, int n_in,
                              void* d_out, int out_size, void* d_ws, size_t ws_size,
                              hipStream_t stream) {
    const float* x       = (const float*)d_in[0];
    const float* w       = (const float*)d_in[1];
    const float* bias    = (const float*)d_in[2];
    const int*   indices = (const int*)d_in[3];
    float*       out     = (float*)d_out;

    const int L = in_sizes[3] / (UNITS_N * NW_N);

    dim3 grid(UNITS_N / U_PER_BLOCK, B_SPLIT);  // (512, 2) = 1024 blocks = 4/CU
    dim3 block(THREADS);                        // 512 threads = 8 waves
    EfficientHashedLinear_72043781423546_kernel<<<grid, block, 0, stream>>>(
        x, w, bias, indices, out, L);
}

// Round 9
// 80.497 us; speedup vs baseline: 1.0293x; 1.0293x over previous
//
#include <hip/hip_runtime.h>

// B=64, D=2048, UNITS=1024, NW=64; L = in_sizes[3]/(UNITS*NW) (~56).
//
// out[b,u] = sum_i x[b,i] * W[u,i] + bias[u], W[u,i] = w[k] where bucket k of
// unit u contains position i (indices 1-shifted, 0 = pad). Buckets partition
// positions per unit -> LDS scatter builds W[u,:] race-free.
//
// R9 vs R8 post-mortem: occupancy is saturated (R3 2w/SIMD=48us, R4 4w=26us,
// R8 8w=28us). R8 doubled per-CU x traffic (U=2) at equal time -> suspect
// per-CU L1-miss/vmem path on x (512 KB/CU in R4, L1=32KB, zero reuse).
// R9 doubles x reuse instead: U=8 -> each x float4 feeds 8 units; logical x
// traffic 128->64 MB, per-wave x loads 32->16. Grid (128,2)=256 blocks x
// 1024 thr, 2 rows/wave, LDS 64KB, live ~80 VGPR (<=128, 4 waves/SIMD).
// A/B: L1-traffic-bound -> kernel ~14-18us; serial-chain-bound -> unchanged.

#define B_DIM   64
#define D_DIM   2048
#define D4      (D_DIM / 4)     // 512 float4 per row
#define UNITS_N 1024
#define NW_N    64
#define U_PER_BLOCK 8
#define B_SPLIT 2
#define B_PER_BLOCK (B_DIM / B_SPLIT)               // 32
#define THREADS 1024
#define WAVES   (THREADS / 64)                      // 16
#define PAIRS_PER_WAVE (U_PER_BLOCK * NW_N / WAVES) // 32
#define ROWS_PER_WAVE  (B_PER_BLOCK / WAVES)        // 2
#define STEPS   (D4 / 64)                           // 8

__global__ __launch_bounds__(THREADS)   // NO 2nd arg: 64-VGPR cap + spill (R5)
void EfficientHashedLinear_72043781423546_kernel(
    const float* __restrict__ x,        // (64, 2048)
    const float* __restrict__ w,        // (64,)
    const float* __restrict__ bias,     // (1024,)
    const int*   __restrict__ indices,  // (UNITS, NW, L) int32
    float*       __restrict__ out,      // (64, 1024)
    int L)
{
    __shared__ float rows[U_PER_BLOCK][D_DIM];   // 64 KB
    __shared__ float w_lds[NW_N];

    const int tid  = threadIdx.x;
    const int wave = tid >> 6;          // 0..15
    const int lane = tid & 63;
    const int u0   = blockIdx.x * U_PER_BLOCK;
    const int bh   = blockIdx.y;        // batch half: 0 or 1

    // Phase 0: zero rows (float4), stage w.
    {
        float4* r4 = (float4*)rows;
        const float4 z = make_float4(0.f, 0.f, 0.f, 0.f);
        #pragma unroll
        for (int i = tid; i < U_PER_BLOCK * D4; i += THREADS)
            r4[i] = z;
        if (tid < NW_N) w_lds[tid] = w[tid];
    }

    // Phase 1a: index load pass — 32 independent lane-predicated loads/wave,
    // all issued before any use (one batched round trip).
    int idxv[PAIRS_PER_WAVE];
    #pragma unroll
    for (int p = 0; p < PAIRS_PER_WAVE; ++p) {
        const int pair = wave * PAIRS_PER_WAVE + p;   // 0..511
        const int uu   = pair >> 6;                   // 0..7
        const int k    = pair & 63;                   // 0..63
        const int* bp  = indices + ((size_t)(u0 + uu) * NW_N + k) * L;
        idxv[p] = (lane < L) ? bp[lane] : 0;
    }

    __syncthreads();   // rows[] zeroed before scatter

    // Phase 1b: scatter pass (LDS only).
    #pragma unroll
    for (int p = 0; p < PAIRS_PER_WAVE; ++p) {
        const int pair = wave * PAIRS_PER_WAVE + p;
        const int uu   = pair >> 6;
        const int k    = pair & 63;
        if (idxv[p] > 0) rows[uu][idxv[p] - 1] = w_lds[k];
    }
    // Generic tail for L > 64 (not expected with this data; kept for safety).
    if (L > 64) {
        #pragma unroll 1
        for (int p = 0; p < PAIRS_PER_WAVE; ++p) {
            const int pair = wave * PAIRS_PER_WAVE + p;
            const int uu   = pair >> 6;
            const int k    = pair & 63;
            const int* bp  = indices + ((size_t)(u0 + uu) * NW_N + k) * L;
            const float wk = w_lds[k];
            for (int l = 64 + lane; l < L; l += 64) {
                int idx = bp[l];
                if (idx > 0) rows[uu][idx - 1] = wk;
            }
        }
    }
    __syncthreads();

    // Phase 2: wave owns 2 batch rows (of this half's 32) x 8 units.
    // Each x float4 feeds 8 units -> 2x the reuse of R4, half the x loads.
    const int b0 = bh * B_PER_BLOCK + wave * ROWS_PER_WAVE;
    const float4* x4 = (const float4*)x;

    float acc[ROWS_PER_WAVE][U_PER_BLOCK];
    #pragma unroll
    for (int bj = 0; bj < ROWS_PER_WAVE; ++bj)
        #pragma unroll
        for (int uu = 0; uu < U_PER_BLOCK; ++uu)
            acc[bj][uu] = 0.0f;

    #pragma unroll 1   // live set ~80 VGPR; big unrolls spill (R2/R5)
    for (int step = 0; step < STEPS; ++step) {
        const int i4 = step * 64 + lane;          // 0..511
        float4 xv[ROWS_PER_WAVE];
        #pragma unroll
        for (int bj = 0; bj < ROWS_PER_WAVE; ++bj)
            xv[bj] = x4[(b0 + bj) * D4 + i4];     // 2 loads, one round trip
        #pragma unroll
        for (int uu = 0; uu < U_PER_BLOCK; ++uu) {
            const float4 rv = ((const float4*)rows[uu])[i4];   // ds_read_b128
            #pragma unroll
            for (int bj = 0; bj < ROWS_PER_WAVE; ++bj) {
                acc[bj][uu] += xv[bj].x * rv.x;
                acc[bj][uu] += xv[bj].y * rv.y;
                acc[bj][uu] += xv[bj].z * rv.z;
                acc[bj][uu] += xv[bj].w * rv.w;
            }
        }
    }

    // Phase 3: butterfly reduce, add bias, store (16 outputs/wave).
    #pragma unroll
    for (int bj = 0; bj < ROWS_PER_WAVE; ++bj) {
        #pragma unroll
        for (int uu = 0; uu < U_PER_BLOCK; ++uu) {
            float v = acc[bj][uu];
            #pragma unroll
            for (int off = 32; off > 0; off >>= 1)
                v += __shfl_down(v, off, 64);
            if (lane == 0)
                out[(b0 + bj) * UNITS_N + (u0 + uu)] = v + bias[u0 + uu];
        }
    }
}

extern "C" void kernel_launch(void* const* d_in, const int* in_sizes, int n_in,
                              void* d_out, int out_size, void* d_ws, size_t ws_size,
                              hipStream_t stream) {
    const float* x       = (const float*)d_in[0];
    const float* w       = (const float*)d_in[1];
    const float* bias    = (const float*)d_in[2];
    const int*   indices = (const int*)d_in[3];
    float*       out     = (float*)d_out;

    const int L = in_sizes[3] / (UNITS_N * NW_N);

    dim3 grid(UNITS_N / U_PER_BLOCK, B_SPLIT);  // (128, 2) = 256 blocks = 1/CU
    dim3 block(THREADS);                        // 1024 threads = 16 waves
    EfficientHashedLinear_72043781423546_kernel<<<grid, block, 0, stream>>>(
        x, w, bias, indices, out, L);
}